// Round 14
// baseline (256.739 us; speedup 1.0000x reference)
//
#include <hip/hip_runtime.h>
#include <hip/hip_bf16.h>

#define BB 64
#define IN_RAW_ 256
#define KIN_ 8448
#define WRW 8192
#define PD_ 2052
#define XW_KS 16

// ---------------------------------------------------------------- xW partial
// xW = ctrl @ W_ih^T ; ctrl = [x | wr] (64 x 8448), W_ih (2048 x 8448)
// grid 256 = 16 col-blocks(128) x 16 k-splits (15x544 + 1x288) = 1 block/CU.
// 64x128 tile, 4x8 per thread: 0.75 B LDS per FLOP (vs 1.0 for 4x4 tile).
__global__ __launch_bounds__(256) void k_xw_partial(
    const float* __restrict__ x, const float* __restrict__ wr,
    const float* __restrict__ Wih, float* __restrict__ xwp) {
  const int cb = blockIdx.x & 15;
  const int ks = blockIdx.x >> 4;
  const int j0 = cb << 7;
  const int k0 = ks * 544;
  const int klen = (ks == 15) ? 288 : 544;
  __shared__ __align__(16) float As[32][68];
  __shared__ __align__(16) float Bs[32][136];
  const int tid = threadIdx.x;
  const int ti = tid & 15, tj = tid >> 4;
  const int lt = tid >> 2, lq = tid & 3;
  float acc[4][8];
#pragma unroll
  for (int i = 0; i < 4; ++i)
#pragma unroll
    for (int j = 0; j < 8; ++j) acc[i][j] = 0.f;
  for (int kc = 0; kc < klen; kc += 32) {
    __syncthreads();
    const int kb = k0 + kc + (lq << 3);
    float va[8], vb0[8], vb1[8];
    if (kb < IN_RAW_) {
      const float* p = x + lt * IN_RAW_ + kb;
#pragma unroll
      for (int u = 0; u < 8; ++u) va[u] = p[u];
    } else {
      const float* p = wr + (size_t)lt * WRW + (kb - IN_RAW_);
#pragma unroll
      for (int u = 0; u < 8; ++u) va[u] = p[u];
    }
    {
      const float* p = Wih + (size_t)(j0 + lt) * KIN_ + kb;
#pragma unroll
      for (int u = 0; u < 8; ++u) vb0[u] = p[u];
      const float* p2 = Wih + (size_t)(j0 + 64 + lt) * KIN_ + kb;
#pragma unroll
      for (int u = 0; u < 8; ++u) vb1[u] = p2[u];
    }
#pragma unroll
    for (int u = 0; u < 8; ++u) As[(lq << 3) + u][lt] = va[u];
#pragma unroll
    for (int u = 0; u < 8; ++u) Bs[(lq << 3) + u][lt] = vb0[u];
#pragma unroll
    for (int u = 0; u < 8; ++u) Bs[(lq << 3) + u][64 + lt] = vb1[u];
    __syncthreads();
#pragma unroll
    for (int kk = 0; kk < 32; ++kk) {
      const float4 a4 = *(const float4*)&As[kk][ti << 2];
      const float4 b4a = *(const float4*)&Bs[kk][tj << 3];
      const float4 b4b = *(const float4*)&Bs[kk][(tj << 3) + 4];
      const float av[4] = {a4.x, a4.y, a4.z, a4.w};
      const float bv[8] = {b4a.x, b4a.y, b4a.z, b4a.w,
                           b4b.x, b4b.y, b4b.z, b4b.w};
#pragma unroll
      for (int i = 0; i < 4; ++i)
#pragma unroll
        for (int j = 0; j < 8; ++j) acc[i][j] = fmaf(av[i], bv[j], acc[i][j]);
    }
  }
#pragma unroll
  for (int i = 0; i < 4; ++i) {
    const int t = (ti << 2) + i;
    float* dst = xwp + (size_t)ks * 131072 + (t << 11) + j0 + (tj << 3);
    *(float4*)(dst) = make_float4(acc[i][0], acc[i][1], acc[i][2], acc[i][3]);
    *(float4*)(dst + 4) = make_float4(acc[i][4], acc[i][5], acc[i][6], acc[i][7]);
  }
}

// ---------------------------------------------------------------- LSTM scan
// (round-8 proven: 124 us) 256 single-wave blocks:
// 0..127 scan; 128..191 bottom-4; 192..255 xW reducers (tagged publish).
__global__ __launch_bounds__(64, 1) void k_scan(
    const float* __restrict__ xwp, const float* __restrict__ bih,
    const float* __restrict__ bhh, const float* __restrict__ Whh,
    const float* __restrict__ h0, const float* __restrict__ c0,
    unsigned long long* __restrict__ ht, unsigned long long* __restrict__ xwt,
    float* __restrict__ out, const float* __restrict__ wu,
    int* __restrict__ t4) {
  const int W = blockIdx.x;
  const int l = threadIdx.x;
  if (W >= 192) {
    const int t = W - 192;
    for (int i = 0; i < 32; ++i) {
      const int col = (i << 6) + l;
      float s = bih[col] + bhh[col];
#pragma unroll
      for (int ks = 0; ks < XW_KS; ++ks)
        s += xwp[(size_t)ks * 131072 + (t << 11) + col];
      const unsigned long long pk =
          (1ull << 32) | (unsigned long long)__float_as_uint(s);
      __hip_atomic_store(xwt + (t << 11) + col, pk, __ATOMIC_RELAXED,
                         __HIP_MEMORY_SCOPE_AGENT);
    }
    return;
  }
  if (W >= 128) {
    const int b = W - 128;
    float val[32];
#pragma unroll
    for (int i = 0; i < 32; ++i) val[i] = wu[(b << 11) + (i << 6) + l];
    for (int pick = 0; pick < 4; ++pick) {
      float bv = 3.4e38f; int bi = -1;
#pragma unroll
      for (int i = 0; i < 32; ++i) {
        const int n = (i << 6) + l;
        const float v = val[i];
        if (v < bv || (v == bv && n > bi)) { bv = v; bi = n; }
      }
#pragma unroll
      for (int s = 1; s < 64; s <<= 1) {
        const float ov = __shfl_xor(bv, s);
        const int oi = __shfl_xor(bi, s);
        if (ov < bv || (ov == bv && oi > bi)) { bv = ov; bi = oi; }
      }
      if (l == 0) t4[(b << 2) + pick] = bi;
      if ((bi & 63) == l) val[bi >> 6] = 3.4e38f;
    }
    return;
  }
  const int d = l & 3;
  const int jj = (W << 2) + d;
  float wreg[16][8];
#pragma unroll
  for (int r = 0; r < 16; ++r) {
    const int row = ((r >> 2) << 9) + (W << 2) + (r & 3);
    const float* p = Whh + ((size_t)row << 9) + (l << 3);
#pragma unroll
    for (int u = 0; u < 8; ++u) wreg[r][u] = p[u];
  }
  float c = 0.f;
  if (l < 4) c = c0[jj];
  float h[8];
#pragma unroll
  for (int u = 0; u < 8; ++u) h[u] = h0[(l << 3) + u];

  for (int t = 0; t < 64; ++t) {
    float xv0 = 0, xv1 = 0, xv2 = 0, xv3 = 0;
    if (l < 4) {
      const unsigned long long* xp = xwt + (t << 11) + jj;
      unsigned long long x0, x1, x2, x3;
      for (;;) {
        x0 = __hip_atomic_load(xp, __ATOMIC_RELAXED, __HIP_MEMORY_SCOPE_AGENT);
        x1 = __hip_atomic_load(xp + 512, __ATOMIC_RELAXED, __HIP_MEMORY_SCOPE_AGENT);
        x2 = __hip_atomic_load(xp + 1024, __ATOMIC_RELAXED, __HIP_MEMORY_SCOPE_AGENT);
        x3 = __hip_atomic_load(xp + 1536, __ATOMIC_RELAXED, __HIP_MEMORY_SCOPE_AGENT);
        if ((unsigned)((x0 & x1 & x2 & x3) >> 32) == 1u) break;
      }
      xv0 = __uint_as_float((unsigned)x0);
      xv1 = __uint_as_float((unsigned)x1);
      xv2 = __uint_as_float((unsigned)x2);
      xv3 = __uint_as_float((unsigned)x3);
    }
    if (t > 0) {
      const unsigned long long* hp = ht + (t << 9) + (l << 3);
      unsigned long long va[8], vb[8];
#pragma unroll
      for (int u = 0; u < 8; ++u)
        va[u] = __hip_atomic_load(hp + u, __ATOMIC_RELAXED, __HIP_MEMORY_SCOPE_AGENT);
      for (;;) {
#pragma unroll
        for (int u = 0; u < 8; ++u)
          vb[u] = __hip_atomic_load(hp + u, __ATOMIC_RELAXED, __HIP_MEMORY_SCOPE_AGENT);
        bool ra = true;
#pragma unroll
        for (int u = 0; u < 8; ++u) ra &= ((unsigned)(va[u] >> 32) == (unsigned)t);
        if (ra) break;
#pragma unroll
        for (int u = 0; u < 8; ++u)
          va[u] = __hip_atomic_load(hp + u, __ATOMIC_RELAXED, __HIP_MEMORY_SCOPE_AGENT);
        bool rb_ = true;
#pragma unroll
        for (int u = 0; u < 8; ++u) rb_ &= ((unsigned)(vb[u] >> 32) == (unsigned)t);
        if (rb_) {
#pragma unroll
          for (int u = 0; u < 8; ++u) va[u] = vb[u];
          break;
        }
      }
#pragma unroll
      for (int u = 0; u < 8; ++u) h[u] = __uint_as_float((unsigned)va[u]);
    }
    float pr[16];
#pragma unroll
    for (int r = 0; r < 16; ++r) {
      float s = 0.f;
#pragma unroll
      for (int u = 0; u < 8; ++u) s = fmaf(wreg[r][u], h[u], s);
      pr[r] = s;
    }
    float v8[8], v4[4], v2[2], v1;
    {
      const bool b0 = (l & 1) != 0;
#pragma unroll
      for (int j = 0; j < 8; ++j) {
        const float keep = b0 ? pr[2 * j + 1] : pr[2 * j];
        const float send = b0 ? pr[2 * j] : pr[2 * j + 1];
        v8[j] = keep + __shfl_xor(send, 1);
      }
    }
    {
      const bool b1 = (l & 2) != 0;
#pragma unroll
      for (int j = 0; j < 4; ++j) {
        const float keep = b1 ? v8[2 * j + 1] : v8[2 * j];
        const float send = b1 ? v8[2 * j] : v8[2 * j + 1];
        v4[j] = keep + __shfl_xor(send, 2);
      }
    }
    {
      const bool b2 = (l & 4) != 0;
#pragma unroll
      for (int j = 0; j < 2; ++j) {
        const float keep = b2 ? v4[2 * j + 1] : v4[2 * j];
        const float send = b2 ? v4[2 * j] : v4[2 * j + 1];
        v2[j] = keep + __shfl_xor(send, 4);
      }
    }
    {
      const bool b3 = (l & 8) != 0;
      const float keep = b3 ? v2[1] : v2[0];
      const float send = b3 ? v2[0] : v2[1];
      v1 = keep + __shfl_xor(send, 8);
    }
    v1 += __shfl_xor(v1, 16);
    v1 += __shfl_xor(v1, 32);
    const float gi_ = __shfl(v1, d);
    const float gf_ = __shfl(v1, d + 4);
    const float gg_ = __shfl(v1, d + 8);
    const float go_ = __shfl(v1, d + 12);
    if (l < 4) {
      const float gi = gi_ + xv0;
      const float gf = gf_ + xv1;
      const float gg = gg_ + xv2;
      const float go = go_ + xv3;
      const float si = 1.f / (1.f + __expf(-gi));
      const float sf = 1.f / (1.f + __expf(-gf));
      const float so = 1.f / (1.f + __expf(-go));
      const float tg = 2.f / (1.f + __expf(-2.f * gg)) - 1.f;
      c = sf * c + si * tg;
      const float tc = 2.f / (1.f + __expf(-2.f * c)) - 1.f;
      const float hnew = so * tc;
      const unsigned long long pk =
          ((unsigned long long)(unsigned)(t + 1) << 32) |
          (unsigned long long)__float_as_uint(hnew);
      __hip_atomic_store(ht + ((t + 1) << 9) + jj, pk, __ATOMIC_RELAXED,
                         __HIP_MEMORY_SCOPE_AGENT);
      out[t * 1536 + jj] = hnew;
    }
  }
}

// ------------------------------------------- param GEMM + activations, fused
__global__ __launch_bounds__(256) void k_param(
    const float* __restrict__ outbuf, const float* __restrict__ Wp,
    const float* __restrict__ bp, float* __restrict__ km,
    float* __restrict__ am, float* __restrict__ sa) {
  const int j0 = blockIdx.x << 6;
  __shared__ __align__(16) float As[32][68];
  __shared__ __align__(16) float Bs[32][68];
  const int tid = threadIdx.x;
  const int ti = tid & 15, tj = tid >> 4;
  const int lt = tid >> 2, lq = tid & 3;
  float acc[4][4];
#pragma unroll
  for (int i = 0; i < 4; ++i)
#pragma unroll
    for (int j = 0; j < 4; ++j) acc[i][j] = 0.f;
  for (int kc = 0; kc < 512; kc += 32) {
    __syncthreads();
    const int kb = kc + (lq << 3);
    float va[8], vb[8];
    {
      const float* p = outbuf + lt * 1536 + kb;
#pragma unroll
      for (int u = 0; u < 8; ++u) va[u] = p[u];
    }
    const int brow = j0 + lt;
    if (brow < PD_) {
      const float* p = Wp + (size_t)brow * 512 + kb;
#pragma unroll
      for (int u = 0; u < 8; ++u) vb[u] = p[u];
    } else {
#pragma unroll
      for (int u = 0; u < 8; ++u) vb[u] = 0.f;
    }
#pragma unroll
    for (int u = 0; u < 8; ++u) As[(lq << 3) + u][lt] = va[u];
#pragma unroll
    for (int u = 0; u < 8; ++u) Bs[(lq << 3) + u][lt] = vb[u];
    __syncthreads();
#pragma unroll
    for (int kk = 0; kk < 32; ++kk) {
      const float4 a4 = *(const float4*)&As[kk][ti << 2];
      const float4 b4 = *(const float4*)&Bs[kk][tj << 2];
      const float av[4] = {a4.x, a4.y, a4.z, a4.w};
      const float bv[4] = {b4.x, b4.y, b4.z, b4.w};
#pragma unroll
      for (int i = 0; i < 4; ++i)
#pragma unroll
        for (int j = 0; j < 4; ++j) acc[i][j] = fmaf(av[i], bv[j], acc[i][j]);
    }
  }
#pragma unroll
  for (int i = 0; i < 4; ++i) {
    const int b = (ti << 2) + i;
#pragma unroll
    for (int j = 0; j < 4; ++j) {
      const int col = j0 + (tj << 2) + j;
      if (col < PD_) {
        const float v = acc[i][j] + bp[col];
        if (col < 1024) km[(b << 10) + col] = tanhf(v);
        else if (col < 2048) am[(b << 10) + col - 1024] = tanhf(v);
        else sa[(b << 2) + col - 2048] = 1.f / (1.f + expf(-v));
      }
    }
  }
}

// ---------------------------- single-pass ip + softmax-exp + PV partials
// lam = cosine similarity in [-1,1] -> exp(lam) needs NO max subtraction.
__global__ __launch_bounds__(256) void k_ipv(
    const float* __restrict__ M, const float* __restrict__ km,
    const float* __restrict__ wr_in, const int* __restrict__ t4,
    float* __restrict__ pacc, float* __restrict__ pscal) {
  const int b = blockIdx.x >> 3;
  const int sl = blockIdx.x & 7;
  const int tid = threadIdx.x;
  const int wv = tid >> 6, l = tid & 63;
  const int g = l >> 4, j = l & 15;
  __shared__ float kns[4];
  __shared__ float t4eL[4][4];
  __shared__ __align__(16) float accW[4][4][256];
  __shared__ float SdW[4][4][4];
  __shared__ float ssW[4][4];
  if (tid < 16) t4eL[tid >> 2][tid & 3] = 0.f;
  {
    const float* kp = km + (((b << 2) + wv) << 8);
    float sq = 0.f;
#pragma unroll
    for (int i = 0; i < 4; ++i) { const float v = kp[l + (i << 6)]; sq = fmaf(v, v, sq); }
    sq += __shfl_xor(sq, 1);  sq += __shfl_xor(sq, 2);  sq += __shfl_xor(sq, 4);
    sq += __shfl_xor(sq, 8);  sq += __shfl_xor(sq, 16); sq += __shfl_xor(sq, 32);
    if (l == 0) kns[wv] = sqrtf(sq);
  }
  float kr[4][16];
#pragma unroll
  for (int r = 0; r < 4; ++r)
#pragma unroll
    for (int cc = 0; cc < 4; ++cc) {
      const float4 kv = *(const float4*)(km + (((b << 2) + r) << 8) + (cc << 6) + (j << 2));
      kr[r][(cc << 2) + 0] = kv.x; kr[r][(cc << 2) + 1] = kv.y;
      kr[r][(cc << 2) + 2] = kv.z; kr[r][(cc << 2) + 3] = kv.w;
    }
  int t4v[4];
#pragma unroll
  for (int ii = 0; ii < 4; ++ii) t4v[ii] = t4[(b << 2) + ii];
  __syncthreads();
  const float kn0 = kns[0], kn1 = kns[1], kn2 = kns[2], kn3 = kns[3];
  float aacc[4][16];
#pragma unroll
  for (int r = 0; r < 4; ++r)
#pragma unroll
    for (int k = 0; k < 16; ++k) aacc[r][k] = 0.f;
  float ssum[4] = {0.f, 0.f, 0.f, 0.f};
  float sdp[4] = {0.f, 0.f, 0.f, 0.f};
  for (int it = 0; it < 16; ++it) {
    const int n = (sl << 8) + (wv << 6) + (it << 2) + g;
    const float* mrow = M + (((size_t)b << 11) + n) * 256;
    float4 m4[4];
#pragma unroll
    for (int cc = 0; cc < 4; ++cc)
      m4[cc] = *(const float4*)(mrow + (cc << 6) + (j << 2));
    float s0 = 0.f, s1 = 0.f, s2 = 0.f, s3 = 0.f, sm = 0.f;
#pragma unroll
    for (int cc = 0; cc < 4; ++cc) {
      const float mv[4] = {m4[cc].x, m4[cc].y, m4[cc].z, m4[cc].w};
#pragma unroll
      for (int e = 0; e < 4; ++e) {
        sm = fmaf(mv[e], mv[e], sm);
        s0 = fmaf(kr[0][(cc << 2) + e], mv[e], s0);
        s1 = fmaf(kr[1][(cc << 2) + e], mv[e], s1);
        s2 = fmaf(kr[2][(cc << 2) + e], mv[e], s2);
        s3 = fmaf(kr[3][(cc << 2) + e], mv[e], s3);
      }
    }
    s0 += __shfl_xor(s0, 1); s0 += __shfl_xor(s0, 2); s0 += __shfl_xor(s0, 4); s0 += __shfl_xor(s0, 8);
    s1 += __shfl_xor(s1, 1); s1 += __shfl_xor(s1, 2); s1 += __shfl_xor(s1, 4); s1 += __shfl_xor(s1, 8);
    s2 += __shfl_xor(s2, 1); s2 += __shfl_xor(s2, 2); s2 += __shfl_xor(s2, 4); s2 += __shfl_xor(s2, 8);
    s3 += __shfl_xor(s3, 1); s3 += __shfl_xor(s3, 2); s3 += __shfl_xor(s3, 4); s3 += __shfl_xor(s3, 8);
    sm += __shfl_xor(sm, 1); sm += __shfl_xor(sm, 2); sm += __shfl_xor(sm, 4); sm += __shfl_xor(sm, 8);
    const float mnv = sqrtf(sm);
    float ev[4];
    ev[0] = __expf(s0 / fmaf(kn0, mnv, 1e-8f));
    ev[1] = __expf(s1 / fmaf(kn1, mnv, 1e-8f));
    ev[2] = __expf(s2 / fmaf(kn2, mnv, 1e-8f));
    ev[3] = __expf(s3 / fmaf(kn3, mnv, 1e-8f));
#pragma unroll
    for (int r = 0; r < 4; ++r) {
      ssum[r] += ev[r];
#pragma unroll
      for (int cc = 0; cc < 4; ++cc) {
        aacc[r][(cc << 2) + 0] = fmaf(ev[r], m4[cc].x, aacc[r][(cc << 2) + 0]);
        aacc[r][(cc << 2) + 1] = fmaf(ev[r], m4[cc].y, aacc[r][(cc << 2) + 1]);
        aacc[r][(cc << 2) + 2] = fmaf(ev[r], m4[cc].z, aacc[r][(cc << 2) + 2]);
        aacc[r][(cc << 2) + 3] = fmaf(ev[r], m4[cc].w, aacc[r][(cc << 2) + 3]);
      }
    }
    if (j < 4) {
      const float wq = wr_in[((size_t)b << 13) + (j << 11) + n];
#pragma unroll
      for (int r = 0; r < 4; ++r) sdp[r] = fmaf(ev[r], wq, sdp[r]);
    }
#pragma unroll
    for (int ii = 0; ii < 4; ++ii)
      if (n == t4v[ii] && j == 0) {
#pragma unroll
        for (int r = 0; r < 4; ++r) t4eL[ii][r] = ev[r];
      }
  }
#pragma unroll
  for (int r = 0; r < 4; ++r) {
    float v = ssum[r];
    v += __shfl_xor(v, 1);  v += __shfl_xor(v, 2);  v += __shfl_xor(v, 4);
    v += __shfl_xor(v, 8);  v += __shfl_xor(v, 16); v += __shfl_xor(v, 32);
    if (l == 0) ssW[wv][r] = v * 0.0625f;
    float sdv = sdp[r];
    sdv += __shfl_xor(sdv, 16);
    sdv += __shfl_xor(sdv, 32);
    if (l < 4) SdW[wv][l][r] = sdv;
  }
#pragma unroll
  for (int r = 0; r < 4; ++r)
#pragma unroll
    for (int k = 0; k < 16; ++k) {
      float v = aacc[r][k];
      v += __shfl_xor(v, 16);
      v += __shfl_xor(v, 32);
      aacc[r][k] = v;
    }
  if (l < 16) {
#pragma unroll
    for (int r = 0; r < 4; ++r)
#pragma unroll
      for (int cc = 0; cc < 4; ++cc)
#pragma unroll
        for (int ee = 0; ee < 4; ++ee)
          accW[wv][r][(cc << 6) + (l << 2) + ee] = aacc[r][(cc << 2) + ee];
  }
  __syncthreads();
  const int slice = (b << 3) + sl;
#pragma unroll
  for (int i = 0; i < 4; ++i) {
    const int e = tid + (i << 8);
    const float s4 = accW[0][i][tid] + accW[1][i][tid] + accW[2][i][tid] + accW[3][i][tid];
    pacc[((size_t)slice << 10) + e] = s4;
  }
  if (tid < 4)
    pscal[(slice << 6) + tid] = ssW[0][tid] + ssW[1][tid] + ssW[2][tid] + ssW[3][tid];
  if (tid < 16) {
    const int r = tid >> 2, q = tid & 3;
    pscal[(slice << 6) + 4 + (r << 2) + q] =
        SdW[0][q][r] + SdW[1][q][r] + SdW[2][q][r] + SdW[3][q][r];
    pscal[(slice << 6) + 20 + tid] = t4eL[tid >> 2][tid & 3];
  }
}

// ---------------------------- finisher: merge 8 slices, normalize, output r_t
__global__ __launch_bounds__(256) void k_fin(
    const float* __restrict__ pacc, const float* __restrict__ pscal,
    const float* __restrict__ sa_g, const float* __restrict__ am,
    const float* __restrict__ M, const int* __restrict__ t4,
    float* __restrict__ out) {
  const int b = blockIdx.x;
  const int tid = threadIdx.x;
  __shared__ float Zs[4], Sl[16], wlu4[4], teL[4][4];
  if (tid < 4) {
    float z = 0.f;
    for (int sl = 0; sl < 8; ++sl) z += pscal[(((b << 3) + sl) << 6) + tid];
    Zs[tid] = z;
  }
  if (tid >= 16 && tid < 32) {
    const int ii = (tid - 16) >> 2, r = (tid - 16) & 3;
    float te = 0.f;
    for (int sl = 0; sl < 8; ++sl)
      te += pscal[(((b << 3) + sl) << 6) + 20 + (ii << 2) + r];
    teL[ii][r] = te;
  }
  __syncthreads();
  if (tid < 16) {
    const int r = tid >> 2, q = tid & 3;
    float sd = 0.f;
    for (int sl = 0; sl < 8; ++sl)
      sd += pscal[(((b << 3) + sl) << 6) + 4 + (r << 2) + q];
    const float Z = Zs[r];
    const float t4s = (teL[0][r] + teL[1][r] + teL[2][r] + teL[3][r]) / Z;
    const float sv = sa_g[(b << 2) + q];
    Sl[(r << 2) + q] = sv * (sd / Z) + (1.f - sv) * t4s;
    if (q == 0) wlu4[r] = teL[0][r] / Z;
  }
  __syncthreads();
  const int luv = t4[b << 2];
#pragma unroll
  for (int i = 0; i < 4; ++i) {
    const int e = tid + (i << 8);
    float s = 0.f;
    for (int sl = 0; sl < 8; ++sl)
      s += pacc[((size_t)(((b << 3) + sl)) << 10) + e];
    s /= Zs[i];
    s -= wlu4[i] * M[(((size_t)b << 11) + luv) * 256 + tid];
#pragma unroll
    for (int q = 0; q < 4; ++q)
      s = fmaf(Sl[(i << 2) + q], am[(((b << 2) + q) << 8) + tid], s);
    out[b * 1536 + 512 + e] = s;
  }
}

extern "C" void kernel_launch(void* const* d_in, const int* in_sizes, int n_in,
                              void* d_out, int out_size, void* d_ws, size_t ws_size,
                              hipStream_t stream) {
  (void)in_sizes; (void)n_in; (void)out_size;
  const float* x   = (const float*)d_in[0];
  const float* M   = (const float*)d_in[1];
  const float* wu  = (const float*)d_in[2];
  const float* wr  = (const float*)d_in[3];
  const float* h0  = (const float*)d_in[4];
  const float* c0  = (const float*)d_in[5];
  const float* Wih = (const float*)d_in[6];
  const float* Whh = (const float*)d_in[7];
  const float* bih = (const float*)d_in[8];
  const float* bhh = (const float*)d_in[9];
  const float* Wp  = (const float*)d_in[10];
  const float* bp  = (const float*)d_in[11];
  float* out = (float*)d_out;
  char* ws = (char*)d_ws;
  if (ws_size < 12457984u) return;

  float* xwp  = (float*)(ws + 0);          // 16*131072*4 = 8,388,608
  float* km   = (float*)(ws + 8388608);    // 262,144
  float* am   = (float*)(ws + 8650752);    // 262,144
  float* sa   = (float*)(ws + 8912896);    // 1,024
  int*   t4   = (int*)(ws + 8913920);      // 1,024
  float* pacc = (float*)(ws + 8914944);    // 2,097,152
  float* pscal= (float*)(ws + 11012096);   // 131,072
  unsigned long long* ht  = (unsigned long long*)(ws + 11143168);  // 266,240
  unsigned long long* xwt = (unsigned long long*)(ws + 11409408);  // 1,048,576

  (void)hipMemsetAsync(ws + 11143168, 0, 266240 + 1048576, stream);
  hipLaunchKernelGGL(k_xw_partial, dim3(256), dim3(256), 0, stream, x, wr, Wih, xwp);
  hipLaunchKernelGGL(k_scan, dim3(256), dim3(64), 0, stream,
                     xwp, bih, bhh, Whh, h0, c0, ht, xwt, out, wu, t4);
  hipLaunchKernelGGL(k_param, dim3(33), dim3(256), 0, stream, out, Wp, bp, km, am, sa);
  hipLaunchKernelGGL(k_ipv, dim3(512), dim3(256), 0, stream, M, km, wr, t4, pacc, pscal);
  hipLaunchKernelGGL(k_fin, dim3(64), dim3(256), 0, stream,
                     pacc, pscal, sa, am, M, t4, out);
}

// Round 15
// 233.397 us; speedup vs baseline: 1.1000x; 1.1000x over previous
//
#include <hip/hip_runtime.h>
#include <hip/hip_bf16.h>

#define BB 64
#define IN_RAW_ 256
#define KIN_ 8448
#define WRW 8192
#define PD_ 2052
#define XW_KS 16

// ---------------------------------------------------------------- xW partial
// xW = ctrl @ W_ih^T ; ctrl = [x | wr] (64 x 8448), W_ih (2048 x 8448)
// grid 552: blocks 0..511 = 32 col-blocks(64) x 16 k-splits (8x544 + 8x512)
//   -> 2 blocks/CU (8 waves) for LDS-latency hiding; 4x4 tile (r13-proven).
// blocks 512..551 zero the ht+xwt sync region (replaces hipMemsetAsync).
__global__ __launch_bounds__(256) void k_xw_partial(
    const float* __restrict__ x, const float* __restrict__ wr,
    const float* __restrict__ Wih, float* __restrict__ xwp,
    float* __restrict__ zbuf) {
  if (blockIdx.x >= 512) {
    // zero 1,314,816 B = 82,176 float4
    float4 z4 = make_float4(0.f, 0.f, 0.f, 0.f);
    float4* z = (float4*)zbuf;
    for (int i = (blockIdx.x - 512) * 256 + threadIdx.x; i < 82176; i += 40 * 256)
      z[i] = z4;
    return;
  }
  const int jb = blockIdx.x & 31;
  const int ks = blockIdx.x >> 5;
  const int j0 = jb << 6;
  const int k0 = (ks < 8) ? ks * 544 : 4352 + ((ks - 8) << 9);
  const int klen = (ks < 8) ? 544 : 512;
  __shared__ __align__(16) float As[32][68];
  __shared__ __align__(16) float Bs[32][68];
  const int tid = threadIdx.x;
  const int ti = tid & 15, tj = tid >> 4;
  const int lt = tid >> 2, lq = tid & 3;
  float acc[4][4];
#pragma unroll
  for (int i = 0; i < 4; ++i)
#pragma unroll
    for (int j = 0; j < 4; ++j) acc[i][j] = 0.f;
  for (int kc = 0; kc < klen; kc += 32) {
    __syncthreads();
    const int kb = k0 + kc + (lq << 3);
    float va[8], vb[8];
    if (kb < IN_RAW_) {
      const float* p = x + lt * IN_RAW_ + kb;
#pragma unroll
      for (int u = 0; u < 8; ++u) va[u] = p[u];
    } else {
      const float* p = wr + (size_t)lt * WRW + (kb - IN_RAW_);
#pragma unroll
      for (int u = 0; u < 8; ++u) va[u] = p[u];
    }
    {
      const float* p = Wih + (size_t)(j0 + lt) * KIN_ + kb;
#pragma unroll
      for (int u = 0; u < 8; ++u) vb[u] = p[u];
    }
#pragma unroll
    for (int u = 0; u < 8; ++u) As[(lq << 3) + u][lt] = va[u];
#pragma unroll
    for (int u = 0; u < 8; ++u) Bs[(lq << 3) + u][lt] = vb[u];
    __syncthreads();
#pragma unroll
    for (int kk = 0; kk < 32; ++kk) {
      const float4 a4 = *(const float4*)&As[kk][ti << 2];
      const float4 b4 = *(const float4*)&Bs[kk][tj << 2];
      const float av[4] = {a4.x, a4.y, a4.z, a4.w};
      const float bv[4] = {b4.x, b4.y, b4.z, b4.w};
#pragma unroll
      for (int i = 0; i < 4; ++i)
#pragma unroll
        for (int j = 0; j < 4; ++j) acc[i][j] = fmaf(av[i], bv[j], acc[i][j]);
    }
  }
#pragma unroll
  for (int i = 0; i < 4; ++i) {
    const int t = (ti << 2) + i;
    float* dst = xwp + (size_t)ks * 131072 + (t << 11) + j0 + (tj << 2);
    dst[0] = acc[i][0]; dst[1] = acc[i][1]; dst[2] = acc[i][2]; dst[3] = acc[i][3];
  }
}

// ---------------------------------------------------------------- LSTM scan
// (round-8/13 proven: 124 us) 256 single-wave blocks:
// 0..127 scan; 128..191 bottom-4; 192..255 xW reducers (tagged publish).
__global__ __launch_bounds__(64, 1) void k_scan(
    const float* __restrict__ xwp, const float* __restrict__ bih,
    const float* __restrict__ bhh, const float* __restrict__ Whh,
    const float* __restrict__ h0, const float* __restrict__ c0,
    unsigned long long* __restrict__ ht, unsigned long long* __restrict__ xwt,
    float* __restrict__ out, const float* __restrict__ wu,
    int* __restrict__ t4) {
  const int W = blockIdx.x;
  const int l = threadIdx.x;
  if (W >= 192) {
    const int t = W - 192;
    for (int i = 0; i < 32; ++i) {
      const int col = (i << 6) + l;
      float s = bih[col] + bhh[col];
#pragma unroll
      for (int ks = 0; ks < XW_KS; ++ks)
        s += xwp[(size_t)ks * 131072 + (t << 11) + col];
      const unsigned long long pk =
          (1ull << 32) | (unsigned long long)__float_as_uint(s);
      __hip_atomic_store(xwt + (t << 11) + col, pk, __ATOMIC_RELAXED,
                         __HIP_MEMORY_SCOPE_AGENT);
    }
    return;
  }
  if (W >= 128) {
    const int b = W - 128;
    float val[32];
#pragma unroll
    for (int i = 0; i < 32; ++i) val[i] = wu[(b << 11) + (i << 6) + l];
    for (int pick = 0; pick < 4; ++pick) {
      float bv = 3.4e38f; int bi = -1;
#pragma unroll
      for (int i = 0; i < 32; ++i) {
        const int n = (i << 6) + l;
        const float v = val[i];
        if (v < bv || (v == bv && n > bi)) { bv = v; bi = n; }
      }
#pragma unroll
      for (int s = 1; s < 64; s <<= 1) {
        const float ov = __shfl_xor(bv, s);
        const int oi = __shfl_xor(bi, s);
        if (ov < bv || (ov == bv && oi > bi)) { bv = ov; bi = oi; }
      }
      if (l == 0) t4[(b << 2) + pick] = bi;
      if ((bi & 63) == l) val[bi >> 6] = 3.4e38f;
    }
    return;
  }
  const int d = l & 3;
  const int jj = (W << 2) + d;
  float wreg[16][8];
#pragma unroll
  for (int r = 0; r < 16; ++r) {
    const int row = ((r >> 2) << 9) + (W << 2) + (r & 3);
    const float* p = Whh + ((size_t)row << 9) + (l << 3);
#pragma unroll
    for (int u = 0; u < 8; ++u) wreg[r][u] = p[u];
  }
  float c = 0.f;
  if (l < 4) c = c0[jj];
  float h[8];
#pragma unroll
  for (int u = 0; u < 8; ++u) h[u] = h0[(l << 3) + u];

  for (int t = 0; t < 64; ++t) {
    float xv0 = 0, xv1 = 0, xv2 = 0, xv3 = 0;
    if (l < 4) {
      const unsigned long long* xp = xwt + (t << 11) + jj;
      unsigned long long x0, x1, x2, x3;
      for (;;) {
        x0 = __hip_atomic_load(xp, __ATOMIC_RELAXED, __HIP_MEMORY_SCOPE_AGENT);
        x1 = __hip_atomic_load(xp + 512, __ATOMIC_RELAXED, __HIP_MEMORY_SCOPE_AGENT);
        x2 = __hip_atomic_load(xp + 1024, __ATOMIC_RELAXED, __HIP_MEMORY_SCOPE_AGENT);
        x3 = __hip_atomic_load(xp + 1536, __ATOMIC_RELAXED, __HIP_MEMORY_SCOPE_AGENT);
        if ((unsigned)((x0 & x1 & x2 & x3) >> 32) == 1u) break;
      }
      xv0 = __uint_as_float((unsigned)x0);
      xv1 = __uint_as_float((unsigned)x1);
      xv2 = __uint_as_float((unsigned)x2);
      xv3 = __uint_as_float((unsigned)x3);
    }
    if (t > 0) {
      const unsigned long long* hp = ht + (t << 9) + (l << 3);
      unsigned long long va[8], vb[8];
#pragma unroll
      for (int u = 0; u < 8; ++u)
        va[u] = __hip_atomic_load(hp + u, __ATOMIC_RELAXED, __HIP_MEMORY_SCOPE_AGENT);
      for (;;) {
#pragma unroll
        for (int u = 0; u < 8; ++u)
          vb[u] = __hip_atomic_load(hp + u, __ATOMIC_RELAXED, __HIP_MEMORY_SCOPE_AGENT);
        bool ra = true;
#pragma unroll
        for (int u = 0; u < 8; ++u) ra &= ((unsigned)(va[u] >> 32) == (unsigned)t);
        if (ra) break;
#pragma unroll
        for (int u = 0; u < 8; ++u)
          va[u] = __hip_atomic_load(hp + u, __ATOMIC_RELAXED, __HIP_MEMORY_SCOPE_AGENT);
        bool rb_ = true;
#pragma unroll
        for (int u = 0; u < 8; ++u) rb_ &= ((unsigned)(vb[u] >> 32) == (unsigned)t);
        if (rb_) {
#pragma unroll
          for (int u = 0; u < 8; ++u) va[u] = vb[u];
          break;
        }
      }
#pragma unroll
      for (int u = 0; u < 8; ++u) h[u] = __uint_as_float((unsigned)va[u]);
    }
    float pr[16];
#pragma unroll
    for (int r = 0; r < 16; ++r) {
      float s = 0.f;
#pragma unroll
      for (int u = 0; u < 8; ++u) s = fmaf(wreg[r][u], h[u], s);
      pr[r] = s;
    }
    float v8[8], v4[4], v2[2], v1;
    {
      const bool b0 = (l & 1) != 0;
#pragma unroll
      for (int j = 0; j < 8; ++j) {
        const float keep = b0 ? pr[2 * j + 1] : pr[2 * j];
        const float send = b0 ? pr[2 * j] : pr[2 * j + 1];
        v8[j] = keep + __shfl_xor(send, 1);
      }
    }
    {
      const bool b1 = (l & 2) != 0;
#pragma unroll
      for (int j = 0; j < 4; ++j) {
        const float keep = b1 ? v8[2 * j + 1] : v8[2 * j];
        const float send = b1 ? v8[2 * j] : v8[2 * j + 1];
        v4[j] = keep + __shfl_xor(send, 2);
      }
    }
    {
      const bool b2 = (l & 4) != 0;
#pragma unroll
      for (int j = 0; j < 2; ++j) {
        const float keep = b2 ? v4[2 * j + 1] : v4[2 * j];
        const float send = b2 ? v4[2 * j] : v4[2 * j + 1];
        v2[j] = keep + __shfl_xor(send, 4);
      }
    }
    {
      const bool b3 = (l & 8) != 0;
      const float keep = b3 ? v2[1] : v2[0];
      const float send = b3 ? v2[0] : v2[1];
      v1 = keep + __shfl_xor(send, 8);
    }
    v1 += __shfl_xor(v1, 16);
    v1 += __shfl_xor(v1, 32);
    const float gi_ = __shfl(v1, d);
    const float gf_ = __shfl(v1, d + 4);
    const float gg_ = __shfl(v1, d + 8);
    const float go_ = __shfl(v1, d + 12);
    if (l < 4) {
      const float gi = gi_ + xv0;
      const float gf = gf_ + xv1;
      const float gg = gg_ + xv2;
      const float go = go_ + xv3;
      const float si = 1.f / (1.f + __expf(-gi));
      const float sf = 1.f / (1.f + __expf(-gf));
      const float so = 1.f / (1.f + __expf(-go));
      const float tg = 2.f / (1.f + __expf(-2.f * gg)) - 1.f;
      c = sf * c + si * tg;
      const float tc = 2.f / (1.f + __expf(-2.f * c)) - 1.f;
      const float hnew = so * tc;
      const unsigned long long pk =
          ((unsigned long long)(unsigned)(t + 1) << 32) |
          (unsigned long long)__float_as_uint(hnew);
      __hip_atomic_store(ht + ((t + 1) << 9) + jj, pk, __ATOMIC_RELAXED,
                         __HIP_MEMORY_SCOPE_AGENT);
      out[t * 1536 + jj] = hnew;
    }
  }
}

// ------------------------------------------- param GEMM + activations, fused
__global__ __launch_bounds__(256) void k_param(
    const float* __restrict__ outbuf, const float* __restrict__ Wp,
    const float* __restrict__ bp, float* __restrict__ km,
    float* __restrict__ am, float* __restrict__ sa) {
  const int j0 = blockIdx.x << 6;
  __shared__ __align__(16) float As[32][68];
  __shared__ __align__(16) float Bs[32][68];
  const int tid = threadIdx.x;
  const int ti = tid & 15, tj = tid >> 4;
  const int lt = tid >> 2, lq = tid & 3;
  float acc[4][4];
#pragma unroll
  for (int i = 0; i < 4; ++i)
#pragma unroll
    for (int j = 0; j < 4; ++j) acc[i][j] = 0.f;
  for (int kc = 0; kc < 512; kc += 32) {
    __syncthreads();
    const int kb = kc + (lq << 3);
    float va[8], vb[8];
    {
      const float* p = outbuf + lt * 1536 + kb;
#pragma unroll
      for (int u = 0; u < 8; ++u) va[u] = p[u];
    }
    const int brow = j0 + lt;
    if (brow < PD_) {
      const float* p = Wp + (size_t)brow * 512 + kb;
#pragma unroll
      for (int u = 0; u < 8; ++u) vb[u] = p[u];
    } else {
#pragma unroll
      for (int u = 0; u < 8; ++u) vb[u] = 0.f;
    }
#pragma unroll
    for (int u = 0; u < 8; ++u) As[(lq << 3) + u][lt] = va[u];
#pragma unroll
    for (int u = 0; u < 8; ++u) Bs[(lq << 3) + u][lt] = vb[u];
    __syncthreads();
#pragma unroll
    for (int kk = 0; kk < 32; ++kk) {
      const float4 a4 = *(const float4*)&As[kk][ti << 2];
      const float4 b4 = *(const float4*)&Bs[kk][tj << 2];
      const float av[4] = {a4.x, a4.y, a4.z, a4.w};
      const float bv[4] = {b4.x, b4.y, b4.z, b4.w};
#pragma unroll
      for (int i = 0; i < 4; ++i)
#pragma unroll
        for (int j = 0; j < 4; ++j) acc[i][j] = fmaf(av[i], bv[j], acc[i][j]);
    }
  }
#pragma unroll
  for (int i = 0; i < 4; ++i) {
    const int b = (ti << 2) + i;
#pragma unroll
    for (int j = 0; j < 4; ++j) {
      const int col = j0 + (tj << 2) + j;
      if (col < PD_) {
        const float v = acc[i][j] + bp[col];
        if (col < 1024) km[(b << 10) + col] = tanhf(v);
        else if (col < 2048) am[(b << 10) + col - 1024] = tanhf(v);
        else sa[(b << 2) + col - 2048] = 1.f / (1.f + expf(-v));
      }
    }
  }
}

// ---------------------------- single-pass ip + softmax-exp + PV partials
// lam = cosine similarity in [-1,1] -> exp(lam) needs NO max subtraction.
__global__ __launch_bounds__(256) void k_ipv(
    const float* __restrict__ M, const float* __restrict__ km,
    const float* __restrict__ wr_in, const int* __restrict__ t4,
    float* __restrict__ pacc, float* __restrict__ pscal) {
  const int b = blockIdx.x >> 3;
  const int sl = blockIdx.x & 7;
  const int tid = threadIdx.x;
  const int wv = tid >> 6, l = tid & 63;
  const int g = l >> 4, j = l & 15;
  __shared__ float kns[4];
  __shared__ float t4eL[4][4];
  __shared__ __align__(16) float accW[4][4][256];
  __shared__ float SdW[4][4][4];
  __shared__ float ssW[4][4];
  if (tid < 16) t4eL[tid >> 2][tid & 3] = 0.f;
  {
    const float* kp = km + (((b << 2) + wv) << 8);
    float sq = 0.f;
#pragma unroll
    for (int i = 0; i < 4; ++i) { const float v = kp[l + (i << 6)]; sq = fmaf(v, v, sq); }
    sq += __shfl_xor(sq, 1);  sq += __shfl_xor(sq, 2);  sq += __shfl_xor(sq, 4);
    sq += __shfl_xor(sq, 8);  sq += __shfl_xor(sq, 16); sq += __shfl_xor(sq, 32);
    if (l == 0) kns[wv] = sqrtf(sq);
  }
  float kr[4][16];
#pragma unroll
  for (int r = 0; r < 4; ++r)
#pragma unroll
    for (int cc = 0; cc < 4; ++cc) {
      const float4 kv = *(const float4*)(km + (((b << 2) + r) << 8) + (cc << 6) + (j << 2));
      kr[r][(cc << 2) + 0] = kv.x; kr[r][(cc << 2) + 1] = kv.y;
      kr[r][(cc << 2) + 2] = kv.z; kr[r][(cc << 2) + 3] = kv.w;
    }
  int t4v[4];
#pragma unroll
  for (int ii = 0; ii < 4; ++ii) t4v[ii] = t4[(b << 2) + ii];
  __syncthreads();
  const float kn0 = kns[0], kn1 = kns[1], kn2 = kns[2], kn3 = kns[3];
  float aacc[4][16];
#pragma unroll
  for (int r = 0; r < 4; ++r)
#pragma unroll
    for (int k = 0; k < 16; ++k) aacc[r][k] = 0.f;
  float ssum[4] = {0.f, 0.f, 0.f, 0.f};
  float sdp[4] = {0.f, 0.f, 0.f, 0.f};
  for (int it = 0; it < 16; ++it) {
    const int n = (sl << 8) + (wv << 6) + (it << 2) + g;
    const float* mrow = M + (((size_t)b << 11) + n) * 256;
    float4 m4[4];
#pragma unroll
    for (int cc = 0; cc < 4; ++cc)
      m4[cc] = *(const float4*)(mrow + (cc << 6) + (j << 2));
    float s0 = 0.f, s1 = 0.f, s2 = 0.f, s3 = 0.f, sm = 0.f;
#pragma unroll
    for (int cc = 0; cc < 4; ++cc) {
      const float mv[4] = {m4[cc].x, m4[cc].y, m4[cc].z, m4[cc].w};
#pragma unroll
      for (int e = 0; e < 4; ++e) {
        sm = fmaf(mv[e], mv[e], sm);
        s0 = fmaf(kr[0][(cc << 2) + e], mv[e], s0);
        s1 = fmaf(kr[1][(cc << 2) + e], mv[e], s1);
        s2 = fmaf(kr[2][(cc << 2) + e], mv[e], s2);
        s3 = fmaf(kr[3][(cc << 2) + e], mv[e], s3);
      }
    }
    s0 += __shfl_xor(s0, 1); s0 += __shfl_xor(s0, 2); s0 += __shfl_xor(s0, 4); s0 += __shfl_xor(s0, 8);
    s1 += __shfl_xor(s1, 1); s1 += __shfl_xor(s1, 2); s1 += __shfl_xor(s1, 4); s1 += __shfl_xor(s1, 8);
    s2 += __shfl_xor(s2, 1); s2 += __shfl_xor(s2, 2); s2 += __shfl_xor(s2, 4); s2 += __shfl_xor(s2, 8);
    s3 += __shfl_xor(s3, 1); s3 += __shfl_xor(s3, 2); s3 += __shfl_xor(s3, 4); s3 += __shfl_xor(s3, 8);
    sm += __shfl_xor(sm, 1); sm += __shfl_xor(sm, 2); sm += __shfl_xor(sm, 4); sm += __shfl_xor(sm, 8);
    const float mnv = sqrtf(sm);
    float ev[4];
    ev[0] = __expf(s0 / fmaf(kn0, mnv, 1e-8f));
    ev[1] = __expf(s1 / fmaf(kn1, mnv, 1e-8f));
    ev[2] = __expf(s2 / fmaf(kn2, mnv, 1e-8f));
    ev[3] = __expf(s3 / fmaf(kn3, mnv, 1e-8f));
#pragma unroll
    for (int r = 0; r < 4; ++r) {
      ssum[r] += ev[r];
#pragma unroll
      for (int cc = 0; cc < 4; ++cc) {
        aacc[r][(cc << 2) + 0] = fmaf(ev[r], m4[cc].x, aacc[r][(cc << 2) + 0]);
        aacc[r][(cc << 2) + 1] = fmaf(ev[r], m4[cc].y, aacc[r][(cc << 2) + 1]);
        aacc[r][(cc << 2) + 2] = fmaf(ev[r], m4[cc].z, aacc[r][(cc << 2) + 2]);
        aacc[r][(cc << 2) + 3] = fmaf(ev[r], m4[cc].w, aacc[r][(cc << 2) + 3]);
      }
    }
    if (j < 4) {
      const float wq = wr_in[((size_t)b << 13) + (j << 11) + n];
#pragma unroll
      for (int r = 0; r < 4; ++r) sdp[r] = fmaf(ev[r], wq, sdp[r]);
    }
#pragma unroll
    for (int ii = 0; ii < 4; ++ii)
      if (n == t4v[ii] && j == 0) {
#pragma unroll
        for (int r = 0; r < 4; ++r) t4eL[ii][r] = ev[r];
      }
  }
#pragma unroll
  for (int r = 0; r < 4; ++r) {
    float v = ssum[r];
    v += __shfl_xor(v, 1);  v += __shfl_xor(v, 2);  v += __shfl_xor(v, 4);
    v += __shfl_xor(v, 8);  v += __shfl_xor(v, 16); v += __shfl_xor(v, 32);
    if (l == 0) ssW[wv][r] = v * 0.0625f;
    float sdv = sdp[r];
    sdv += __shfl_xor(sdv, 16);
    sdv += __shfl_xor(sdv, 32);
    if (l < 4) SdW[wv][l][r] = sdv;
  }
#pragma unroll
  for (int r = 0; r < 4; ++r)
#pragma unroll
    for (int k = 0; k < 16; ++k) {
      float v = aacc[r][k];
      v += __shfl_xor(v, 16);
      v += __shfl_xor(v, 32);
      aacc[r][k] = v;
    }
  if (l < 16) {
#pragma unroll
    for (int r = 0; r < 4; ++r)
#pragma unroll
      for (int cc = 0; cc < 4; ++cc)
#pragma unroll
        for (int ee = 0; ee < 4; ++ee)
          accW[wv][r][(cc << 6) + (l << 2) + ee] = aacc[r][(cc << 2) + ee];
  }
  __syncthreads();
  const int slice = (b << 3) + sl;
#pragma unroll
  for (int i = 0; i < 4; ++i) {
    const int e = tid + (i << 8);
    const float s4 = accW[0][i][tid] + accW[1][i][tid] + accW[2][i][tid] + accW[3][i][tid];
    pacc[((size_t)slice << 10) + e] = s4;
  }
  if (tid < 4)
    pscal[(slice << 6) + tid] = ssW[0][tid] + ssW[1][tid] + ssW[2][tid] + ssW[3][tid];
  if (tid < 16) {
    const int r = tid >> 2, q = tid & 3;
    pscal[(slice << 6) + 4 + (r << 2) + q] =
        SdW[0][q][r] + SdW[1][q][r] + SdW[2][q][r] + SdW[3][q][r];
    pscal[(slice << 6) + 20 + tid] = t4eL[tid >> 2][tid & 3];
  }
}

// ---------------------------- finisher: merge 8 slices, normalize, output r_t
__global__ __launch_bounds__(256) void k_fin(
    const float* __restrict__ pacc, const float* __restrict__ pscal,
    const float* __restrict__ sa_g, const float* __restrict__ am,
    const float* __restrict__ M, const int* __restrict__ t4,
    float* __restrict__ out) {
  const int b = blockIdx.x;
  const int tid = threadIdx.x;
  __shared__ float Zs[4], Sl[16], wlu4[4], teL[4][4];
  if (tid < 4) {
    float z = 0.f;
    for (int sl = 0; sl < 8; ++sl) z += pscal[(((b << 3) + sl) << 6) + tid];
    Zs[tid] = z;
  }
  if (tid >= 16 && tid < 32) {
    const int ii = (tid - 16) >> 2, r = (tid - 16) & 3;
    float te = 0.f;
    for (int sl = 0; sl < 8; ++sl)
      te += pscal[(((b << 3) + sl) << 6) + 20 + (ii << 2) + r];
    teL[ii][r] = te;
  }
  __syncthreads();
  if (tid < 16) {
    const int r = tid >> 2, q = tid & 3;
    float sd = 0.f;
    for (int sl = 0; sl < 8; ++sl)
      sd += pscal[(((b << 3) + sl) << 6) + 4 + (r << 2) + q];
    const float Z = Zs[r];
    const float t4s = (teL[0][r] + teL[1][r] + teL[2][r] + teL[3][r]) / Z;
    const float sv = sa_g[(b << 2) + q];
    Sl[(r << 2) + q] = sv * (sd / Z) + (1.f - sv) * t4s;
    if (q == 0) wlu4[r] = teL[0][r] / Z;
  }
  __syncthreads();
  const int luv = t4[b << 2];
#pragma unroll
  for (int i = 0; i < 4; ++i) {
    const int e = tid + (i << 8);
    float s = 0.f;
    for (int sl = 0; sl < 8; ++sl)
      s += pacc[((size_t)(((b << 3) + sl)) << 10) + e];
    s /= Zs[i];
    s -= wlu4[i] * M[(((size_t)b << 11) + luv) * 256 + tid];
#pragma unroll
    for (int q = 0; q < 4; ++q)
      s = fmaf(Sl[(i << 2) + q], am[(((b << 2) + q) << 8) + tid], s);
    out[b * 1536 + 512 + e] = s;
  }
}

extern "C" void kernel_launch(void* const* d_in, const int* in_sizes, int n_in,
                              void* d_out, int out_size, void* d_ws, size_t ws_size,
                              hipStream_t stream) {
  (void)in_sizes; (void)n_in; (void)out_size;
  const float* x   = (const float*)d_in[0];
  const float* M   = (const float*)d_in[1];
  const float* wu  = (const float*)d_in[2];
  const float* wr  = (const float*)d_in[3];
  const float* h0  = (const float*)d_in[4];
  const float* c0  = (const float*)d_in[5];
  const float* Wih = (const float*)d_in[6];
  const float* Whh = (const float*)d_in[7];
  const float* bih = (const float*)d_in[8];
  const float* bhh = (const float*)d_in[9];
  const float* Wp  = (const float*)d_in[10];
  const float* bp  = (const float*)d_in[11];
  float* out = (float*)d_out;
  char* ws = (char*)d_ws;
  if (ws_size < 12457984u) return;

  float* xwp  = (float*)(ws + 0);          // 16*131072*4 = 8,388,608
  float* km   = (float*)(ws + 8388608);    // 262,144
  float* am   = (float*)(ws + 8650752);    // 262,144
  float* sa   = (float*)(ws + 8912896);    // 1,024
  int*   t4   = (int*)(ws + 8913920);      // 1,024
  float* pacc = (float*)(ws + 8914944);    // 2,097,152
  float* pscal= (float*)(ws + 11012096);   // 131,072
  unsigned long long* ht  = (unsigned long long*)(ws + 11143168);  // 266,240
  unsigned long long* xwt = (unsigned long long*)(ws + 11409408);  // 1,048,576
  float* zbuf = (float*)(ws + 11143168);   // ht+xwt region, 1,314,816 B

  hipLaunchKernelGGL(k_xw_partial, dim3(552), dim3(256), 0, stream, x, wr, Wih, xwp, zbuf);
  hipLaunchKernelGGL(k_scan, dim3(256), dim3(64), 0, stream,
                     xwp, bih, bhh, Whh, h0, c0, ht, xwt, out, wu, t4);
  hipLaunchKernelGGL(k_param, dim3(33), dim3(256), 0, stream, out, Wp, bp, km, am, sa);
  hipLaunchKernelGGL(k_ipv, dim3(512), dim3(256), 0, stream, M, km, wr, t4, pacc, pscal);
  hipLaunchKernelGGL(k_fin, dim3(64), dim3(256), 0, stream,
                     pacc, pscal, sa, am, M, t4, out);
}